// Round 18
// baseline (156.322 us; speedup 1.0000x reference)
//
#include <hip/hip_runtime.h>
#include <math.h>

typedef __attribute__((ext_vector_type(8))) short short8;
typedef __attribute__((ext_vector_type(4))) float f32x4;

namespace {
constexpr int BATCH = 4096;
constexpr int SEQT  = 256;
constexpr int INSZ  = 24;
constexpr int H     = 40;
constexpr int NOUT  = 24;
constexpr int R     = 16;    // rows per block = 4 waves x 4 rows; grid = 256
constexpr int NT    = 256;

__device__ __forceinline__ unsigned short f2bf(float f) {
  unsigned int u = __float_as_uint(f);
  return (unsigned short)((u + 0x7FFFu + ((u >> 16) & 1u)) >> 16);  // RNE
}
__device__ __forceinline__ unsigned short cvt_bf16(float f) {
  float r;
  asm("v_cvt_pk_bf16_f32 %0, %1, %2" : "=v"(r) : "v"(f), "v"(f));
  return (unsigned short)__float_as_uint(r);
}
__device__ __forceinline__ unsigned int cvt_pk2(float lo, float hi) {
  float r;
  asm("v_cvt_pk_bf16_f32 %0, %1, %2" : "=v"(r) : "v"(lo), "v"(hi));
  return __float_as_uint(r);
}
__device__ __forceinline__ float4 ld4(const float* p) {
  return *reinterpret_cast<const float4*>(p);
}
__device__ __forceinline__ float sigm(float v) {
  return __builtin_amdgcn_rcpf(1.0f + __builtin_amdgcn_exp2f(v * -1.442695041f));
}
__device__ __forceinline__ float tanh_fast(float v) {
  return fmaf(2.0f,
              __builtin_amdgcn_rcpf(1.0f + __builtin_amdgcn_exp2f(v * -2.885390082f)),
              -1.0f);
}
}  // namespace

#define MFMA16(A, Bf, C) __builtin_amdgcn_mfma_f32_16x16x32_bf16((A), (Bf), (C), 0, 0, 0)
// compiler-level ordering fence for same-wave LDS write->read (HW DS pipe is
// in-order within a wave; this stops the compiler from reordering)
#define FENCE() asm volatile("" ::: "memory")

// ZERO-BARRIER GRU: each wave fully owns 4 batch rows — computes ALL 40 units
// (3 u-tiles x 7 MFMAs) AND the FC for those rows. The h(t) ds_write -> A(t+1)
// ds_read dependency is in-wave (same-wave DS ops execute in order), so the
// kernel has NO s_barrier / __syncthreads at all. The per-step cross-wave
// convergence that bounded R4..R17 is gone; 4 independent wave-chains per CU.
// Real rows at A-rows {0,4,8,12} (= lq*4, acc elem 0): 1 gate item/lane/tile.
// FC trick: FC(t-1) reuses the A(t) registers (F's x-rows are zero, h-part is
// h(t-1)) — no extra LDS reads, MFMAs independent of the gate chain.
// Buffer layout per wave (2KB, ushort idx wb=w<<10): row-major [16][64] bf16,
// swizzle idx^=(row&7)<<3; k: [x(t) 0..23 | h(t-1) 24..63]; pad rows zero.
__global__ __launch_bounds__(NT, 1) void gru_nobar(
    const float* __restrict__ x, const float* __restrict__ Wih,
    const float* __restrict__ Whh, const float* __restrict__ bih,
    const float* __restrict__ bhh, const float* __restrict__ Wfc,
    const float* __restrict__ bfc, float* __restrict__ out,
    float* __restrict__ hid) {
  __shared__ __align__(16) unsigned short Abuf[4 * 1024];  // 2KB per wave

  const int tid = threadIdx.x;
  const int l   = tid & 63;
  const int w   = tid >> 6;
  const int lm  = l & 15;
  const int lq  = l >> 4;
  const int wb  = w << 10;                 // wave buffer base (ushort idx)
  const int gb0 = blockIdx.x * R + w * 4;  // wave's first batch row

  // zero own buffer (2KB = 64 lanes x 2 uint4)
  reinterpret_cast<uint4*>(&Abuf[wb])[l]      = make_uint4(0, 0, 0, 0);
  reinterpret_cast<uint4*>(&Abuf[wb])[l + 64] = make_uint4(0, 0, 0, 0);

  const int aBase0 = wb + ((lm * 64 + lq * 8)      ^ ((lm & 7) << 3));
  const int aBase1 = wb + ((lm * 64 + lq * 8 + 32) ^ ((lm & 7) << 3));

  // ---- gate weights: ALL 3 u-tiles per lane (u_g = g*16+lm) ----
  short8 B[3][4][2];
  float bias[3][4];
  float hold[3] = {0, 0, 0};
  int aw[3];
  bool gv[3];
#pragma unroll
  for (int g = 0; g < 3; ++g) {
    const int u = g * 16 + lm;
    const bool val = (u < H);
    gv[g] = val;
#pragma unroll
    for (int z = 0; z < 4; ++z) {
#pragma unroll
      for (int kt = 0; kt < 2; ++kt) {
        short8 b;
#pragma unroll
        for (int j = 0; j < 8; ++j) {
          const int k = kt * 32 + lq * 8 + j;
          float v = 0.0f;
          if (val) {
            if (z == 0)      v = (k < 24) ? Wih[u * 24 + k]        : Whh[u * 40 + (k - 24)];
            else if (z == 1) v = (k < 24) ? Wih[(40 + u) * 24 + k] : Whh[(40 + u) * 40 + (k - 24)];
            else if (z == 2) v = (k < 24) ? Wih[(80 + u) * 24 + k] : 0.0f;
            else             v = (k < 24) ? 0.0f                   : Whh[(80 + u) * 40 + (k - 24)];
          }
          b[j] = (short)f2bf(v);
        }
        B[g][z][kt] = b;
      }
    }
    bias[g][0] = val ? bih[u] + bhh[u] : 0.0f;
    bias[g][1] = val ? bih[40 + u] + bhh[40 + u] : 0.0f;
    bias[g][2] = val ? bih[80 + u] : 0.0f;   // n input bias
    bias[g][3] = val ? bhh[80 + u] : 0.0f;   // n hidden bias (scaled by r)
    const int arow = lq * 4;                 // real row (acc elem 0)
    aw[g] = wb + ((arow * 64 + 24 + u) ^ ((arow & 7) << 3));
  }

  // ---- FC weights (all lanes; o = f*16+lm) ----
  short8 F[2][2];
  float biasF[2];
#pragma unroll
  for (int f = 0; f < 2; ++f) {
    const int o = f * 16 + lm;
#pragma unroll
    for (int kt = 0; kt < 2; ++kt) {
      short8 b;
#pragma unroll
      for (int j = 0; j < 8; ++j) {
        const int k = kt * 32 + lq * 8 + j;
        const float v = (o < NOUT && k >= 24) ? Wfc[o * H + (k - 24)] : 0.0f;
        b[j] = (short)f2bf(v);
      }
      F[f][kt] = b;
    }
    biasF[f] = (o < NOUT) ? bfc[o] : 0.0f;
  }
  float* orow = out + ((size_t)(gb0 + lq) * SEQT) * NOUT;

  // ---- x staging (own rows): lanes l<24, row xr = l/6, A-row 4*xr ----
  const bool xv = (l < 24);
  const int xr = l / 6, xc = (l - xr * 6) * 4;
  const float* xp = xv ? (x + ((size_t)(gb0 + xr) * SEQT) * INSZ + xc) : nullptr;
  const int xw = wb + (((xr * 4) * 64 + xc) ^ (((xr * 4) & 7) << 3));

  const f32x4 kZero = {0.0f, 0.0f, 0.0f, 0.0f};

  // depth-4 x prefetch: xQj holds x(T) with T === j (mod 4)
  float4 xQ1 = make_float4(0,0,0,0), xQ2 = make_float4(0,0,0,0);
  float4 xQ3 = make_float4(0,0,0,0), xQ0 = make_float4(0,0,0,0);
  if (xv) {   // stage x(0); prefetch x(1..4)
    const float4 v0 = ld4(xp);
    *reinterpret_cast<uint2*>(&Abuf[xw]) =
        make_uint2(cvt_pk2(v0.x, v0.y), cvt_pk2(v0.z, v0.w));
    xQ1 = ld4(xp + 1 * INSZ);
    xQ2 = ld4(xp + 2 * INSZ);
    xQ3 = ld4(xp + 3 * INSZ);
    xQ0 = ld4(xp + 4 * INSZ);
  }
  FENCE();
  short8 A0 = *reinterpret_cast<const short8*>(&Abuf[aBase0]);  // A(0)
  short8 A1 = *reinterpret_cast<const short8*>(&Abuf[aBase1]);

// One recurrence step. On entry A0/A1 = A(T) = [x(T) | h(T-1)].
// Emits: 21 gate MFMAs + 4 FC MFMAs (computing FC(T-1), stored if T>0),
// gate epilogue (1 item/lane/tile), h(T)+x(T+1) writes, reads A(T+1).
#define STEP(T, XS)                                                             \
  {                                                                             \
    f32x4 ar0 = MFMA16(A0, B[0][0][0], kZero);                                  \
    f32x4 az0 = MFMA16(A0, B[0][1][0], kZero);                                  \
    f32x4 ax0 = MFMA16(A0, B[0][2][0], kZero);                                  \
    f32x4 ah0 = MFMA16(A0, B[0][3][0], kZero);                                  \
    f32x4 ar1 = MFMA16(A0, B[1][0][0], kZero);                                  \
    f32x4 az1 = MFMA16(A0, B[1][1][0], kZero);                                  \
    f32x4 ax1 = MFMA16(A0, B[1][2][0], kZero);                                  \
    f32x4 ah1 = MFMA16(A0, B[1][3][0], kZero);                                  \
    f32x4 ar2 = MFMA16(A0, B[2][0][0], kZero);                                  \
    f32x4 az2 = MFMA16(A0, B[2][1][0], kZero);                                  \
    f32x4 ax2 = MFMA16(A0, B[2][2][0], kZero);                                  \
    f32x4 ah2 = MFMA16(A0, B[2][3][0], kZero);                                  \
    f32x4 ff0 = MFMA16(A0, F[0][0], kZero);                                     \
    f32x4 ff1 = MFMA16(A0, F[1][0], kZero);                                     \
    ar0 = MFMA16(A1, B[0][0][1], ar0);                                          \
    az0 = MFMA16(A1, B[0][1][1], az0);                                          \
    ah0 = MFMA16(A1, B[0][3][1], ah0);                                          \
    ar1 = MFMA16(A1, B[1][0][1], ar1);                                          \
    az1 = MFMA16(A1, B[1][1][1], az1);                                          \
    ah1 = MFMA16(A1, B[1][3][1], ah1);                                          \
    ar2 = MFMA16(A1, B[2][0][1], ar2);                                          \
    az2 = MFMA16(A1, B[2][1][1], az2);                                          \
    ah2 = MFMA16(A1, B[2][3][1], ah2);                                          \
    ff0 = MFMA16(A1, F[0][1], ff0);                                             \
    ff1 = MFMA16(A1, F[1][1], ff1);                                             \
    if ((T) > 0) {  /* store FC(T-1) */                                         \
      const size_t toff = (size_t)((T) - 1) * NOUT;                             \
      orow[toff + lm] = sigm(ff0[0] + biasF[0]);                                \
      if (lm < 8) orow[toff + 16 + lm] = sigm(ff1[0] + biasF[1]);               \
    }                                                                           \
    {                                                                           \
      const float rr = sigm(ar0[0] + bias[0][0]);                               \
      const float zz = sigm(az0[0] + bias[0][1]);                               \
      const float nn = tanh_fast(fmaf(rr, ah0[0] + bias[0][3], ax0[0] + bias[0][2])); \
      const float h  = fmaf(zz, hold[0] - nn, nn);                              \
      hold[0] = h;                                                              \
      Abuf[aw[0]] = cvt_bf16(h);                                                \
    }                                                                           \
    {                                                                           \
      const float rr = sigm(ar1[0] + bias[1][0]);                               \
      const float zz = sigm(az1[0] + bias[1][1]);                               \
      const float nn = tanh_fast(fmaf(rr, ah1[0] + bias[1][3], ax1[0] + bias[1][2])); \
      const float h  = fmaf(zz, hold[1] - nn, nn);                              \
      hold[1] = h;                                                              \
      Abuf[aw[1]] = cvt_bf16(h);                                                \
    }                                                                           \
    {                                                                           \
      const float rr = sigm(ar2[0] + bias[2][0]);                               \
      const float zz = sigm(az2[0] + bias[2][1]);                               \
      const float nn = tanh_fast(fmaf(rr, ah2[0] + bias[2][3], ax2[0] + bias[2][2])); \
      const float h  = fmaf(zz, hold[2] - nn, nn);                              \
      hold[2] = h;                                                              \
      if (gv[2]) Abuf[aw[2]] = cvt_bf16(h);                                     \
    }                                                                           \
    if (xv) {                                                                   \
      if ((T) + 1 < SEQT)                                                       \
        *reinterpret_cast<uint2*>(&Abuf[xw]) =                                  \
            make_uint2(cvt_pk2(XS.x, XS.y), cvt_pk2(XS.z, XS.w));               \
      if ((T) + 5 < SEQT) XS = ld4(xp + (size_t)((T) + 5) * INSZ);              \
    }                                                                           \
    FENCE();                                                                    \
    A0 = *reinterpret_cast<const short8*>(&Abuf[aBase0]);                       \
    A1 = *reinterpret_cast<const short8*>(&Abuf[aBase1]);                       \
  }

  for (int tt = 0; tt < SEQT; tt += 4) {
    STEP(tt + 0, xQ1)
    STEP(tt + 1, xQ2)
    STEP(tt + 2, xQ3)
    STEP(tt + 3, xQ0)
  }

  // final FC(255): A0/A1 = [stale x | h(255)]; F's x-rows are zero
  {
    f32x4 ff0 = MFMA16(A0, F[0][0], kZero);
    f32x4 ff1 = MFMA16(A0, F[1][0], kZero);
    ff0 = MFMA16(A1, F[0][1], ff0);
    ff1 = MFMA16(A1, F[1][1], ff1);
    const size_t toff = (size_t)(SEQT - 1) * NOUT;
    orow[toff + lm] = sigm(ff0[0] + biasF[0]);
    if (lm < 8) orow[toff + 16 + lm] = sigm(ff1[0] + biasF[1]);
  }

  // final hidden state
#pragma unroll
  for (int g = 0; g < 3; ++g)
    if (gv[g]) hid[(size_t)(gb0 + lq) * H + (g * 16 + lm)] = hold[g];
}

extern "C" void kernel_launch(void* const* d_in, const int* in_sizes, int n_in,
                              void* d_out, int out_size, void* d_ws, size_t ws_size,
                              hipStream_t stream) {
  const float* x   = (const float*)d_in[0];
  const float* Wih = (const float*)d_in[1];
  const float* Whh = (const float*)d_in[2];
  const float* bih = (const float*)d_in[3];
  const float* bhh = (const float*)d_in[4];
  const float* Wfc = (const float*)d_in[5];
  const float* bfc = (const float*)d_in[6];
  float* out = (float*)d_out;
  float* hid = out + (size_t)BATCH * SEQT * NOUT;

  dim3 grid(BATCH / R);
  dim3 block(NT);
  hipLaunchKernelGGL(gru_nobar, grid, block, 0, stream,
                     x, Wih, Whh, bih, bhh, Wfc, bfc, out, hid);
}

// Round 19
// 112.561 us; speedup vs baseline: 1.3888x; 1.3888x over previous
//
#include <hip/hip_runtime.h>
#include <math.h>

typedef __attribute__((ext_vector_type(8))) short short8;
typedef __attribute__((ext_vector_type(4))) float f32x4;

namespace {
constexpr int BATCH = 4096;
constexpr int SEQT  = 256;
constexpr int INSZ  = 24;
constexpr int H     = 40;
constexpr int NOUT  = 24;
constexpr int R     = 8;     // rows per block, grid = 512 (2 independent blocks/CU)
constexpr int NT    = 256;   // 4 waves: 0-2 gate tiles, 3 = x-stage + FC(lagged)

__device__ __forceinline__ unsigned short f2bf(float f) {
  unsigned int u = __float_as_uint(f);
  return (unsigned short)((u + 0x7FFFu + ((u >> 16) & 1u)) >> 16);  // RNE
}
__device__ __forceinline__ unsigned short cvt_bf16(float f) {
  float r;
  asm("v_cvt_pk_bf16_f32 %0, %1, %2" : "=v"(r) : "v"(f), "v"(f));
  return (unsigned short)__float_as_uint(r);   // low 16 bits = bf16(f), RNE
}
__device__ __forceinline__ unsigned int cvt_pk2(float lo, float hi) {
  float r;
  asm("v_cvt_pk_bf16_f32 %0, %1, %2" : "=v"(r) : "v"(lo), "v"(hi));
  return __float_as_uint(r);   // {bf16(hi), bf16(lo)}
}
__device__ __forceinline__ float4 ld4(const float* p) {
  return *reinterpret_cast<const float4*>(p);
}
// Native-rate transcendentals (v_exp_f32/v_rcp_f32) — avoids IEEE div sequence.
__device__ __forceinline__ float sigm(float v) {
  return __builtin_amdgcn_rcpf(1.0f + __builtin_amdgcn_exp2f(v * -1.442695041f));
}
__device__ __forceinline__ float tanh_fast(float v) {
  return fmaf(2.0f,
              __builtin_amdgcn_rcpf(1.0f + __builtin_amdgcn_exp2f(v * -2.885390082f)),
              -1.0f);
}
}  // namespace

// Raw barrier: drain only LDS ops; global loads/stores stay in flight.
#define BAR()                                              \
  asm volatile("s_waitcnt lgkmcnt(0)" ::: "memory");       \
  __builtin_amdgcn_s_barrier();                            \
  __builtin_amdgcn_sched_barrier(0);

// FINAL (R15 structure — measured optimum of the decomposition family):
// 2 independent 8-row blocks per CU (grid=512). Cross-block phase drift hides
// the per-step latency chain (R8 showed same-block lockstep waves cannot; R13
// showed 4 blocks over-subscribe the DS pipe; R16-R18 showed in-wave ILP and
// barrier-free structures regress). Real rows at A-rows lq*4+{0,1}; pad rows
// zero forever. Zero-C MFMA chains with bias in the scalar epilogue; 7 MFMAs
// (nx kt=1 tile identically zero); native exp2/rcp gate math; depth-4 x
// prefetch; raw lgkm-only barrier.
__global__ __launch_bounds__(NT) void gru_mfma4(
    const float* __restrict__ x, const float* __restrict__ Wih,
    const float* __restrict__ Whh, const float* __restrict__ bih,
    const float* __restrict__ bhh, const float* __restrict__ Wfc,
    const float* __restrict__ bfc, float* __restrict__ out,
    float* __restrict__ hid) {
  __shared__ __align__(16) unsigned short Abuf[2 * 1024];

  const int tid = threadIdx.x;
  const int l   = tid & 63;
  const int w   = tid >> 6;
  const int lm  = l & 15;
  const int lq  = l >> 4;
  const int gb0 = blockIdx.x * R;

  reinterpret_cast<uint4*>(Abuf)[tid] = make_uint4(0, 0, 0, 0);  // zero both buffers

  const int aBase0 = ((lm * 64 + lq * 8)      ^ ((lm & 7) << 3));
  const int aBase1 = ((lm * 64 + lq * 8 + 32) ^ ((lm & 7) << 3));

  // ---------------- gate role (waves 0..2) ----------------
  short8 B[4][2];
  float bias[4] = {0, 0, 0, 0};
  float hold[2] = {0, 0};
  int aw[2] = {0, 0};
  int u = 0;
  bool gvalid = false;
  if (w < 3) {
    u = w * 16 + lm;
    gvalid = (u < H);
#pragma unroll
    for (int z = 0; z < 4; ++z) {
#pragma unroll
      for (int kt = 0; kt < 2; ++kt) {
        short8 b;
#pragma unroll
        for (int j = 0; j < 8; ++j) {
          const int k = kt * 32 + lq * 8 + j;
          float v = 0.0f;
          if (gvalid) {
            if (z == 0)      v = (k < 24) ? Wih[u * 24 + k]          : Whh[u * 40 + (k - 24)];
            else if (z == 1) v = (k < 24) ? Wih[(40 + u) * 24 + k]   : Whh[(40 + u) * 40 + (k - 24)];
            else if (z == 2) v = (k < 24) ? Wih[(80 + u) * 24 + k]   : 0.0f;
            else             v = (k < 24) ? 0.0f                     : Whh[(80 + u) * 40 + (k - 24)];
          }
          b[j] = (short)f2bf(v);
        }
        B[z][kt] = b;
      }
    }
    if (gvalid) {
      bias[0] = bih[u] + bhh[u];
      bias[1] = bih[40 + u] + bhh[40 + u];
      bias[2] = bih[80 + u];           // n input bias
      bias[3] = bhh[80 + u];           // n hidden bias (scaled by r)
    }
#pragma unroll
    for (int i = 0; i < 2; ++i) {
      const int arow = lq * 4 + i;     // real rows live at acc rows {0,1}
      aw[i] = ((arow * 64 + 24 + u) ^ ((arow & 7) << 3));
    }
  }

  // ---------------- x-stage + FC role (wave 3) ----------------
  short8 F[2][2];
  float biasF[2] = {0, 0};
  float* orow[2] = {nullptr, nullptr};
  const float* xp0 = nullptr;
  int xw0 = 0;
  bool xv = false;
  // depth-4 x prefetch: xQj holds x(T) with T === j (mod 4)
  float4 xQ1 = make_float4(0,0,0,0), xQ2 = make_float4(0,0,0,0);
  float4 xQ3 = make_float4(0,0,0,0), xQ0 = make_float4(0,0,0,0);
  if (w == 3) {
#pragma unroll
    for (int f = 0; f < 2; ++f) {
      const int o = f * 16 + lm;
#pragma unroll
      for (int kt = 0; kt < 2; ++kt) {
        short8 b;
#pragma unroll
        for (int j = 0; j < 8; ++j) {
          const int k = kt * 32 + lq * 8 + j;
          const float v = (o < NOUT && k >= 24) ? Wfc[o * H + (k - 24)] : 0.0f;
          b[j] = (short)f2bf(v);
        }
        F[f][kt] = b;
      }
      biasF[f] = (o < NOUT) ? bfc[o] : 0.0f;
    }
#pragma unroll
    for (int i = 0; i < 2; ++i)
      orow[i] = out + ((size_t)(gb0 + lq * 2 + i) * SEQT) * NOUT;

    // x staging: 48 float4 chunks (8 rows x 6), lanes l<48; row r -> A-row
    // ar = (r>>1)*4 + (r&1)
    xv = (l < 48);
    const int xr = l / 6, xc = (l - xr * 6) * 4;
    const int ar_ = ((xr >> 1) << 2) + (xr & 1);
    if (xv) xp0 = x + ((size_t)(gb0 + xr) * SEQT) * INSZ + xc;
    xw0 = ((ar_ * 64 + xc) ^ ((ar_ & 7) << 3));
  }

  // persistent zero C for all MFMAs — never written, no per-step acc init
  const f32x4 kZero = {0.0f, 0.0f, 0.0f, 0.0f};

  __syncthreads();  // zero-init visible

  if (w == 3 && xv) {  // stage x(0) into buf0; prefetch x(1..4)
    const float4 v0 = ld4(xp0);
    *reinterpret_cast<uint2*>(&Abuf[xw0]) =
        make_uint2(cvt_pk2(v0.x, v0.y), cvt_pk2(v0.z, v0.w));
    xQ1 = ld4(xp0 + 1 * INSZ);
    xQ2 = ld4(xp0 + 2 * INSZ);
    xQ3 = ld4(xp0 + 3 * INSZ);
    xQ0 = ld4(xp0 + 4 * INSZ);
  }
  __syncthreads();  // x(0) staged

// 7-MFMA gate step, zero-C chained (acc regs never re-initialized); biases
// added on the 2 real elements in the epilogue. nx kt=1 tile identically zero.
#define GATE_STEP(BO, NBO)                                                      \
  if (w < 3) {                                                                  \
    const short8 A0 = *reinterpret_cast<const short8*>(&Abuf[(BO) + aBase0]);   \
    const short8 A1 = *reinterpret_cast<const short8*>(&Abuf[(BO) + aBase1]);   \
    f32x4 ar = __builtin_amdgcn_mfma_f32_16x16x32_bf16(A0, B[0][0], kZero, 0, 0, 0); \
    f32x4 az = __builtin_amdgcn_mfma_f32_16x16x32_bf16(A0, B[1][0], kZero, 0, 0, 0); \
    f32x4 ax = __builtin_amdgcn_mfma_f32_16x16x32_bf16(A0, B[2][0], kZero, 0, 0, 0); \
    f32x4 ah = __builtin_amdgcn_mfma_f32_16x16x32_bf16(A0, B[3][0], kZero, 0, 0, 0); \
    ar = __builtin_amdgcn_mfma_f32_16x16x32_bf16(A1, B[0][1], ar, 0, 0, 0);     \
    az = __builtin_amdgcn_mfma_f32_16x16x32_bf16(A1, B[1][1], az, 0, 0, 0);     \
    ah = __builtin_amdgcn_mfma_f32_16x16x32_bf16(A1, B[3][1], ah, 0, 0, 0);     \
    _Pragma("unroll")                                                           \
    for (int i = 0; i < 2; ++i) {                                               \
      const float rr = sigm(ar[i] + bias[0]);                                   \
      const float zz = sigm(az[i] + bias[1]);                                   \
      const float nn = tanh_fast(fmaf(rr, ah[i] + bias[3], ax[i] + bias[2]));   \
      const float h  = fmaf(zz, hold[i] - nn, nn);                              \
      hold[i] = h;                                                              \
      if (gvalid) Abuf[(NBO) + aw[i]] = cvt_bf16(h);                            \
    }                                                                           \
  }

// stage x(T) into buffer TBO from reg XS; reload XS <- x(T+4)
#define XSTAGE(T, TBO, XS)                                                      \
  if (xv) {                                                                     \
    if ((T) < SEQT) {                                                           \
      *reinterpret_cast<uint2*>(&Abuf[(TBO) + xw0]) =                           \
          make_uint2(cvt_pk2(XS.x, XS.y), cvt_pk2(XS.z, XS.w));                 \
    }                                                                           \
    if ((T) + 4 < SEQT) XS = ld4(xp0 + (size_t)((T) + 4) * INSZ);               \
  }

// FC for step T, reading buffer BO (= buffer holding h(T)); zero-C chained,
// bias added in epilogue; 2 real rows/lane
#define FC_STEP(T, BO)                                                          \
  {                                                                             \
    const short8 hA0 = *reinterpret_cast<const short8*>(&Abuf[(BO) + aBase0]);  \
    const short8 hA1 = *reinterpret_cast<const short8*>(&Abuf[(BO) + aBase1]);  \
    f32x4 f0 = __builtin_amdgcn_mfma_f32_16x16x32_bf16(hA0, F[0][0], kZero, 0, 0, 0); \
    f32x4 f1 = __builtin_amdgcn_mfma_f32_16x16x32_bf16(hA0, F[1][0], kZero, 0, 0, 0); \
    f0 = __builtin_amdgcn_mfma_f32_16x16x32_bf16(hA1, F[0][1], f0, 0, 0, 0);    \
    f1 = __builtin_amdgcn_mfma_f32_16x16x32_bf16(hA1, F[1][1], f1, 0, 0, 0);    \
    _Pragma("unroll")                                                           \
    for (int i = 0; i < 2; ++i) {                                               \
      orow[i][(size_t)(T) * NOUT + lm] = sigm(f0[i] + biasF[0]);                \
      if (lm < 8) orow[i][(size_t)(T) * NOUT + 16 + lm] = sigm(f1[i] + biasF[1]); \
    }                                                                           \
  }

  for (int tt = 0; tt < SEQT; tt += 4) {
    // ---- interval tt: bo=0, nbo=1024 ----
    GATE_STEP(0, 1024)
    if (w == 3) {
      XSTAGE(tt + 1, 1024, xQ1)
      if (tt > 0) FC_STEP(tt - 1, 0)
    }
    BAR()
    // ---- interval tt+1: bo=1024, nbo=0 ----
    GATE_STEP(1024, 0)
    if (w == 3) {
      XSTAGE(tt + 2, 0, xQ2)
      FC_STEP(tt, 1024)
    }
    BAR()
    // ---- interval tt+2: bo=0, nbo=1024 ----
    GATE_STEP(0, 1024)
    if (w == 3) {
      XSTAGE(tt + 3, 1024, xQ3)
      FC_STEP(tt + 1, 0)
    }
    BAR()
    // ---- interval tt+3: bo=1024, nbo=0 ----
    GATE_STEP(1024, 0)
    if (w == 3) {
      XSTAGE(tt + 4, 0, xQ0)
      FC_STEP(tt + 2, 1024)
    }
    BAR()
  }
  // epilogue: FC for the final step (h(255) lives in buf0)
  if (w == 3) FC_STEP(SEQT - 1, 0)

  // final hidden state from registers (2 real rows per lane)
  if (w < 3 && gvalid) {
#pragma unroll
    for (int i = 0; i < 2; ++i)
      hid[(size_t)(gb0 + lq * 2 + i) * H + u] = hold[i];
  }
}

extern "C" void kernel_launch(void* const* d_in, const int* in_sizes, int n_in,
                              void* d_out, int out_size, void* d_ws, size_t ws_size,
                              hipStream_t stream) {
  const float* x   = (const float*)d_in[0];
  const float* Wih = (const float*)d_in[1];
  const float* Whh = (const float*)d_in[2];
  const float* bih = (const float*)d_in[3];
  const float* bhh = (const float*)d_in[4];
  const float* Wfc = (const float*)d_in[5];
  const float* bfc = (const float*)d_in[6];
  float* out = (float*)d_out;
  float* hid = out + (size_t)BATCH * SEQT * NOUT;

  dim3 grid(BATCH / R);
  dim3 block(NT);
  hipLaunchKernelGGL(gru_mfma4, grid, block, 0, stream,
                     x, Wih, Whh, bih, bhh, Wfc, bfc, out, hid);
}